// Round 1
// baseline (5356.194 us; speedup 1.0000x reference)
//
#include <hip/hip_runtime.h>

// GRU-GAN generator, MI355X.
// B=512 rows, H=64, S=2048 steps, F=32 outputs.
// Parallelism: 256 blocks x 512 threads; block handles 2 batch rows (independent
// recurrences). 8 waves, wave-specialized:
//   waves 0-5: (dir, gate) gate dot-products, weight rows resident in VGPRs
//   waves 6-7: latent linear + leaky + fused out-projection + sigmoid + store
// Barriers: 3 per step, matched counts across the two divergent wave loops
// (wave-uniform branching; each wave executes exactly 3 s_barriers/iteration).

#define NB 512
#define NH 64
#define NS 2048
#define NF 32

__device__ __forceinline__ float lk(float v) { return fmaxf(v, 0.01f * v); }

__device__ __forceinline__ float sigm(float v) {
    float e = __expf(-v);
    return __builtin_amdgcn_rcpf(1.f + e);
}

__device__ __forceinline__ float tanh_fast(float v) {
    // tanh(v) = 1 - 2/(exp(2v)+1); exp overflow -> inf -> rcp -> 0 -> 1 (correct limit)
    float e = __expf(v + v);
    return 1.f - 2.f * __builtin_amdgcn_rcpf(e + 1.f);
}

__global__ __launch_bounds__(512, 2)
void grugan_kernel(const float* __restrict__ noise,
                   const float* __restrict__ Wihf, const float* __restrict__ Whhf,
                   const float* __restrict__ bihf, const float* __restrict__ bhhf,
                   const float* __restrict__ Wihb, const float* __restrict__ Whhb,
                   const float* __restrict__ bihb, const float* __restrict__ bhhb,
                   const float* __restrict__ Wlat, const float* __restrict__ blat,
                   const float* __restrict__ Wout, const float* __restrict__ bout,
                   float* __restrict__ out)
{
    __shared__ float xbuf[2][NH];         // [row][i]  current x (lat after ONE leaky)
    __shared__ float hbuf[2][2][NH];      // [dir][row][i]
    __shared__ float rzbuf[2][2][2][NH];  // [dir][gate r=0/z=1][row][i]

    const int tid  = threadIdx.x;
    const int wave = tid >> 6;
    const int lane = tid & 63;
    const int row0 = blockIdx.x * 2;

    // init state: x0 = 0, h_fwd = h_bwd = noise
    if (wave == 0) {
        xbuf[0][lane] = 0.f;
        xbuf[1][lane] = 0.f;
    } else if (wave <= 4) {
        int d = (wave - 1) >> 1, r = (wave - 1) & 1;
        hbuf[d][r][lane] = noise[(row0 + r) * NH + lane];
    }
    __syncthreads();

    if (wave < 6) {
        // ---------------- gate waves ----------------
        const int dir = wave / 3;   // 0 fwd, 1 bwd
        const int g   = wave % 3;   // 0=r 1=z 2=n
        const int j   = g * 64 + lane;
        const float* Wih = dir ? Wihb : Wihf;
        const float* Whh = dir ? Whhb : Whhf;

        float wih[64], whh[64];
        const float4* wi4 = (const float4*)(Wih + j * 64);
        const float4* wh4 = (const float4*)(Whh + j * 64);
#pragma unroll
        for (int c = 0; c < 16; ++c) {
            float4 a = wi4[c];
            wih[4*c+0] = a.x; wih[4*c+1] = a.y; wih[4*c+2] = a.z; wih[4*c+3] = a.w;
            float4 b = wh4[c];
            whh[4*c+0] = b.x; whh[4*c+1] = b.y; whh[4*c+2] = b.z; whh[4*c+3] = b.w;
        }
        const float bi = (dir ? bihb : bihf)[j];
        const float bh = (dir ? bhhb : bhhf)[j];

        float h0 = 0.f, h1 = 0.f;   // n-wave keeps its hidden state in registers
        if (g == 2) {
            h0 = noise[(row0 + 0) * NH + lane];
            h1 = noise[(row0 + 1) * NH + lane];
        }

        const float4* x0p = (const float4*)xbuf[0];
        const float4* x1p = (const float4*)xbuf[1];
        const float4* h0p = (const float4*)hbuf[dir][0];
        const float4* h1p = (const float4*)hbuf[dir][1];

        for (int t = 0; t < NS; ++t) {
            float ai0 = 0.f, ai1 = 0.f, ah0 = 0.f, ah1 = 0.f;
#pragma unroll
            for (int c = 0; c < 16; ++c) {
                const float4 xa = x0p[c];
                const float4 xb = x1p[c];
                const float4 ha = h0p[c];
                const float4 hc = h1p[c];
                ai0 = fmaf(wih[4*c+0], xa.x, ai0);
                ai0 = fmaf(wih[4*c+1], xa.y, ai0);
                ai0 = fmaf(wih[4*c+2], xa.z, ai0);
                ai0 = fmaf(wih[4*c+3], xa.w, ai0);
                ai1 = fmaf(wih[4*c+0], xb.x, ai1);
                ai1 = fmaf(wih[4*c+1], xb.y, ai1);
                ai1 = fmaf(wih[4*c+2], xb.z, ai1);
                ai1 = fmaf(wih[4*c+3], xb.w, ai1);
                ah0 = fmaf(whh[4*c+0], ha.x, ah0);
                ah0 = fmaf(whh[4*c+1], ha.y, ah0);
                ah0 = fmaf(whh[4*c+2], ha.z, ah0);
                ah0 = fmaf(whh[4*c+3], ha.w, ah0);
                ah1 = fmaf(whh[4*c+0], hc.x, ah1);
                ah1 = fmaf(whh[4*c+1], hc.y, ah1);
                ah1 = fmaf(whh[4*c+2], hc.z, ah1);
                ah1 = fmaf(whh[4*c+3], hc.w, ah1);
            }
            if (g < 2) {
                rzbuf[dir][g][0][lane] = sigm(ai0 + ah0 + bi + bh);
                rzbuf[dir][g][1][lane] = sigm(ai1 + ah1 + bi + bh);
            }
            __syncthreads();   // A: r,z visible
            if (g == 2) {
                float r0 = rzbuf[dir][0][0][lane], r1 = rzbuf[dir][0][1][lane];
                float z0 = rzbuf[dir][1][0][lane], z1 = rzbuf[dir][1][1][lane];
                float n0 = tanh_fast(ai0 + bi + r0 * (ah0 + bh));
                float n1 = tanh_fast(ai1 + bi + r1 * (ah1 + bh));
                h0 = n0 + z0 * (h0 - n0);   // (1-z)*n + z*h
                h1 = n1 + z1 * (h1 - n1);
                hbuf[dir][0][lane] = h0;
                hbuf[dir][1][lane] = h1;
            }
            __syncthreads();   // B: h' visible
            __syncthreads();   // C: x (next input) visible
        }
    } else {
        // ---------------- latent / output waves (wave 6: row 0, wave 7: row 1) ----------------
        const int row  = wave - 6;
        const int grow = row0 + row;

        float wl[128];
        const float4* wl4 = (const float4*)(Wlat + lane * 128);
#pragma unroll
        for (int c = 0; c < 32; ++c) {
            float4 a = wl4[c];
            wl[4*c+0] = a.x; wl[4*c+1] = a.y; wl[4*c+2] = a.z; wl[4*c+3] = a.w;
        }
        const float bl = blat[lane];

        const int f = lane & 31, half = lane >> 5;
        float wo[32];
        const float4* wo4 = (const float4*)(Wout + f * 64 + half * 32);
#pragma unroll
        for (int c = 0; c < 8; ++c) {
            float4 a = wo4[c];
            wo[4*c+0] = a.x; wo[4*c+1] = a.y; wo[4*c+2] = a.z; wo[4*c+3] = a.w;
        }
        const float bo = bout[f];
        float* orow = out + (size_t)grow * NS * NF;

        const float4* hf4 = (const float4*)hbuf[0][row];
        const float4* hb4 = (const float4*)hbuf[1][row];
        const float4* xr4 = (const float4*)xbuf[row];

        for (int t = 0; t < NS; ++t) {
            __syncthreads();   // A
            __syncthreads();   // B: h' ready
            float acc = bl;
#pragma unroll
            for (int c = 0; c < 16; ++c) {
                const float4 v = hf4[c];
                acc = fmaf(wl[4*c+0], v.x, acc);
                acc = fmaf(wl[4*c+1], v.y, acc);
                acc = fmaf(wl[4*c+2], v.z, acc);
                acc = fmaf(wl[4*c+3], v.w, acc);
            }
#pragma unroll
            for (int c = 0; c < 16; ++c) {
                const float4 v = hb4[c];
                acc = fmaf(wl[64+4*c+0], v.x, acc);
                acc = fmaf(wl[64+4*c+1], v.y, acc);
                acc = fmaf(wl[64+4*c+2], v.z, acc);
                acc = fmaf(wl[64+4*c+3], v.w, acc);
            }
            float la = lk(acc);          // first leaky -> recurrent x and ys[t]
            xbuf[row][lane] = la;
            __syncthreads();   // C: x published
            // fused epilogue: second leaky + Linear(H->F) + sigmoid, overlaps next gate phase
            float po = 0.f;
#pragma unroll
            for (int c = 0; c < 8; ++c) {
                const float4 v = xr4[half * 8 + c];
                po = fmaf(wo[4*c+0], lk(v.x), po);
                po = fmaf(wo[4*c+1], lk(v.y), po);
                po = fmaf(wo[4*c+2], lk(v.z), po);
                po = fmaf(wo[4*c+3], lk(v.w), po);
            }
            po += __shfl_xor(po, 32);
            float y = sigm(po + bo);
            if (half == 0) orow[t * NF + f] = y;
        }
    }
}

extern "C" void kernel_launch(void* const* d_in, const int* in_sizes, int n_in,
                              void* d_out, int out_size, void* d_ws, size_t ws_size,
                              hipStream_t stream) {
    const float* noise = (const float*)d_in[0];
    const float* Wihf  = (const float*)d_in[1];
    const float* Whhf  = (const float*)d_in[2];
    const float* bihf  = (const float*)d_in[3];
    const float* bhhf  = (const float*)d_in[4];
    const float* Wihb  = (const float*)d_in[5];
    const float* Whhb  = (const float*)d_in[6];
    const float* bihb  = (const float*)d_in[7];
    const float* bhhb  = (const float*)d_in[8];
    const float* Wlat  = (const float*)d_in[9];
    const float* blat  = (const float*)d_in[10];
    const float* Wout  = (const float*)d_in[11];
    const float* bout  = (const float*)d_in[12];

    grugan_kernel<<<dim3(NB / 2), dim3(512), 0, stream>>>(
        noise, Wihf, Whhf, bihf, bhhf, Wihb, Whhb, bihb, bhhb,
        Wlat, blat, Wout, bout, (float*)d_out);
}

// Round 2
// 3418.517 us; speedup vs baseline: 1.5668x; 1.5668x over previous
//
#include <hip/hip_runtime.h>

// GRU-GAN generator, MI355X. Round 2.
// B=512 rows, H=64, S=2048 steps, F=32 outputs.
// 256 blocks x 512 threads; block = 2 batch rows. 8 waves, specialized:
//   waves 0-5: (dir, gate) dot-products, weight rows resident in VGPRs
//   waves 6-7: latent linear + leaky + fused out-projection + sigmoid + store
// R2 changes vs R1:
//   * amdgpu_waves_per_eu(2,2): allocator gets the full 256-VGPR budget so the
//     128 weight floats per gate lane actually stay register-resident
//     (R1: VGPR_Count=124 -> in-loop reloads, FETCH_SIZE ~1 GB).
//   * gate h-dots moved into the barrier-B..C window so they overlap the
//     latent wave's x computation; only x-dots remain after barrier C.
//   * latent dot uses 4 accumulators (R1: single 128-deep FMA chain).
// Barriers: 3/step, matched counts across all wave-uniform divergent paths.

#define NB 512
#define NH 64
#define NS 2048
#define NF 32

__device__ __forceinline__ float lk(float v) { return fmaxf(v, 0.01f * v); }

__device__ __forceinline__ float sigm(float v) {
    float e = __expf(-v);
    return __builtin_amdgcn_rcpf(1.f + e);
}

__device__ __forceinline__ float tanh_fast(float v) {
    // tanh(v) = 1 - 2/(exp(2v)+1); exp overflow -> inf -> rcp -> 0 -> 1 (correct limit)
    float e = __expf(v + v);
    return 1.f - 2.f * __builtin_amdgcn_rcpf(e + 1.f);
}

__global__ __launch_bounds__(512)
__attribute__((amdgpu_waves_per_eu(2, 2)))
void grugan_kernel(const float* __restrict__ noise,
                   const float* __restrict__ Wihf, const float* __restrict__ Whhf,
                   const float* __restrict__ bihf, const float* __restrict__ bhhf,
                   const float* __restrict__ Wihb, const float* __restrict__ Whhb,
                   const float* __restrict__ bihb, const float* __restrict__ bhhb,
                   const float* __restrict__ Wlat, const float* __restrict__ blat,
                   const float* __restrict__ Wout, const float* __restrict__ bout,
                   float* __restrict__ out)
{
    __shared__ float xbuf[2][NH];         // [row][i]  x(t) = lat after ONE leaky
    __shared__ float hbuf[2][2][NH];      // [dir][row][i] h(t)
    __shared__ float rzbuf[2][2][2][NH];  // [dir][gate r=0/z=1][row][i]

    const int tid  = threadIdx.x;
    const int wave = tid >> 6;
    const int lane = tid & 63;
    const int row0 = blockIdx.x * 2;

    // init: x0 = 0, h_fwd = h_bwd = noise
    if (wave == 0) {
        xbuf[0][lane] = 0.f;
        xbuf[1][lane] = 0.f;
    } else if (wave <= 4) {
        int d = (wave - 1) >> 1, r = (wave - 1) & 1;
        hbuf[d][r][lane] = noise[(row0 + r) * NH + lane];
    }
    __syncthreads();

    if (wave < 6) {
        // ---------------- gate waves ----------------
        const int dir = wave / 3;   // 0 fwd, 1 bwd
        const int g   = wave % 3;   // 0=r 1=z 2=n
        const int j   = g * 64 + lane;
        const float* Wih = dir ? Wihb : Wihf;
        const float* Whh = dir ? Whhb : Whhf;

        float wih[64], whh[64];
        const float4* wi4 = (const float4*)(Wih + j * 64);
        const float4* wh4 = (const float4*)(Whh + j * 64);
#pragma unroll
        for (int c = 0; c < 16; ++c) {
            float4 a = wi4[c];
            wih[4*c+0] = a.x; wih[4*c+1] = a.y; wih[4*c+2] = a.z; wih[4*c+3] = a.w;
            float4 b = wh4[c];
            whh[4*c+0] = b.x; whh[4*c+1] = b.y; whh[4*c+2] = b.z; whh[4*c+3] = b.w;
        }
        const float bi = (dir ? bihb : bihf)[j];
        const float bh = (dir ? bhhb : bhhf)[j];

        float h0 = 0.f, h1 = 0.f;   // n-wave keeps hidden state in registers
        if (g == 2) {
            h0 = noise[(row0 + 0) * NH + lane];
            h1 = noise[(row0 + 1) * NH + lane];
        }

        const float4* x0p = (const float4*)xbuf[0];
        const float4* x1p = (const float4*)xbuf[1];
        const float4* h0p = (const float4*)hbuf[dir][0];
        const float4* h1p = (const float4*)hbuf[dir][1];

        // --- prologue: h-dots for t=0 from initial h (= noise) ---
        float ah0 = 0.f, ah1 = 0.f;
#pragma unroll
        for (int c = 0; c < 16; ++c) {
            const float4 ha = h0p[c];
            const float4 hc = h1p[c];
            ah0 = fmaf(whh[4*c+0], ha.x, ah0);
            ah0 = fmaf(whh[4*c+1], ha.y, ah0);
            ah0 = fmaf(whh[4*c+2], ha.z, ah0);
            ah0 = fmaf(whh[4*c+3], ha.w, ah0);
            ah1 = fmaf(whh[4*c+0], hc.x, ah1);
            ah1 = fmaf(whh[4*c+1], hc.y, ah1);
            ah1 = fmaf(whh[4*c+2], hc.z, ah1);
            ah1 = fmaf(whh[4*c+3], hc.w, ah1);
        }

        for (int t = 0; t < NS; ++t) {
            // x(t) is ready (barrier C of prev step / init). x-dots:
            float ai0 = 0.f, ai1 = 0.f;
#pragma unroll
            for (int c = 0; c < 16; ++c) {
                const float4 xa = x0p[c];
                const float4 xb = x1p[c];
                ai0 = fmaf(wih[4*c+0], xa.x, ai0);
                ai0 = fmaf(wih[4*c+1], xa.y, ai0);
                ai0 = fmaf(wih[4*c+2], xa.z, ai0);
                ai0 = fmaf(wih[4*c+3], xa.w, ai0);
                ai1 = fmaf(wih[4*c+0], xb.x, ai1);
                ai1 = fmaf(wih[4*c+1], xb.y, ai1);
                ai1 = fmaf(wih[4*c+2], xb.z, ai1);
                ai1 = fmaf(wih[4*c+3], xb.w, ai1);
            }
            if (g < 2) {
                rzbuf[dir][g][0][lane] = sigm(ai0 + ah0 + bi + bh);
                rzbuf[dir][g][1][lane] = sigm(ai1 + ah1 + bi + bh);
            }
            __syncthreads();   // A: r,z visible
            if (g == 2) {
                float r0 = rzbuf[dir][0][0][lane], r1 = rzbuf[dir][0][1][lane];
                float z0 = rzbuf[dir][1][0][lane], z1 = rzbuf[dir][1][1][lane];
                float n0 = tanh_fast(ai0 + bi + r0 * (ah0 + bh));
                float n1 = tanh_fast(ai1 + bi + r1 * (ah1 + bh));
                h0 = n0 + z0 * (h0 - n0);   // (1-z)*n + z*h
                h1 = n1 + z1 * (h1 - n1);
                hbuf[dir][0][lane] = h0;
                hbuf[dir][1][lane] = h1;
            }
            __syncthreads();   // B: h(t+1) visible
            // h-dots for step t+1 — overlaps latent wave computing x(t+1)
            ah0 = 0.f; ah1 = 0.f;
#pragma unroll
            for (int c = 0; c < 16; ++c) {
                const float4 ha = h0p[c];
                const float4 hc = h1p[c];
                ah0 = fmaf(whh[4*c+0], ha.x, ah0);
                ah0 = fmaf(whh[4*c+1], ha.y, ah0);
                ah0 = fmaf(whh[4*c+2], ha.z, ah0);
                ah0 = fmaf(whh[4*c+3], ha.w, ah0);
                ah1 = fmaf(whh[4*c+0], hc.x, ah1);
                ah1 = fmaf(whh[4*c+1], hc.y, ah1);
                ah1 = fmaf(whh[4*c+2], hc.z, ah1);
                ah1 = fmaf(whh[4*c+3], hc.w, ah1);
            }
            __syncthreads();   // C: x(t+1) visible
        }
    } else {
        // ---------------- latent/output waves (wave 6: row 0, wave 7: row 1) ----------------
        const int row  = wave - 6;
        const int grow = row0 + row;

        float wl[128];
        const float4* wl4 = (const float4*)(Wlat + lane * 128);
#pragma unroll
        for (int c = 0; c < 32; ++c) {
            float4 a = wl4[c];
            wl[4*c+0] = a.x; wl[4*c+1] = a.y; wl[4*c+2] = a.z; wl[4*c+3] = a.w;
        }
        const float bl = blat[lane];

        const int f = lane & 31, half = lane >> 5;
        float wo[32];
        const float4* wo4 = (const float4*)(Wout + f * 64 + half * 32);
#pragma unroll
        for (int c = 0; c < 8; ++c) {
            float4 a = wo4[c];
            wo[4*c+0] = a.x; wo[4*c+1] = a.y; wo[4*c+2] = a.z; wo[4*c+3] = a.w;
        }
        const float bo = bout[f];
        float* orow = out + (size_t)grow * NS * NF;

        const float4* hf4 = (const float4*)hbuf[0][row];
        const float4* hb4 = (const float4*)hbuf[1][row];
        const float4* xr4 = (const float4*)xbuf[row];

        for (int t = 0; t < NS; ++t) {
            __syncthreads();   // A
            __syncthreads();   // B: h(t+1) ready
            // latent dot, 4 independent accumulator chains
            float a0 = bl, a1 = 0.f, a2 = 0.f, a3 = 0.f;
#pragma unroll
            for (int c = 0; c < 4; ++c) {
                const float4 v0 = hf4[4*c+0];
                const float4 v1 = hf4[4*c+1];
                const float4 v2 = hf4[4*c+2];
                const float4 v3 = hf4[4*c+3];
                a0 = fmaf(wl[16*c+ 0], v0.x, a0);
                a0 = fmaf(wl[16*c+ 1], v0.y, a0);
                a0 = fmaf(wl[16*c+ 2], v0.z, a0);
                a0 = fmaf(wl[16*c+ 3], v0.w, a0);
                a1 = fmaf(wl[16*c+ 4], v1.x, a1);
                a1 = fmaf(wl[16*c+ 5], v1.y, a1);
                a1 = fmaf(wl[16*c+ 6], v1.z, a1);
                a1 = fmaf(wl[16*c+ 7], v1.w, a1);
                a2 = fmaf(wl[16*c+ 8], v2.x, a2);
                a2 = fmaf(wl[16*c+ 9], v2.y, a2);
                a2 = fmaf(wl[16*c+10], v2.z, a2);
                a2 = fmaf(wl[16*c+11], v2.w, a2);
                a3 = fmaf(wl[16*c+12], v3.x, a3);
                a3 = fmaf(wl[16*c+13], v3.y, a3);
                a3 = fmaf(wl[16*c+14], v3.z, a3);
                a3 = fmaf(wl[16*c+15], v3.w, a3);
            }
#pragma unroll
            for (int c = 0; c < 4; ++c) {
                const float4 v0 = hb4[4*c+0];
                const float4 v1 = hb4[4*c+1];
                const float4 v2 = hb4[4*c+2];
                const float4 v3 = hb4[4*c+3];
                a0 = fmaf(wl[64+16*c+ 0], v0.x, a0);
                a0 = fmaf(wl[64+16*c+ 1], v0.y, a0);
                a0 = fmaf(wl[64+16*c+ 2], v0.z, a0);
                a0 = fmaf(wl[64+16*c+ 3], v0.w, a0);
                a1 = fmaf(wl[64+16*c+ 4], v1.x, a1);
                a1 = fmaf(wl[64+16*c+ 5], v1.y, a1);
                a1 = fmaf(wl[64+16*c+ 6], v1.z, a1);
                a1 = fmaf(wl[64+16*c+ 7], v1.w, a1);
                a2 = fmaf(wl[64+16*c+ 8], v2.x, a2);
                a2 = fmaf(wl[64+16*c+ 9], v2.y, a2);
                a2 = fmaf(wl[64+16*c+10], v2.z, a2);
                a2 = fmaf(wl[64+16*c+11], v2.w, a2);
                a3 = fmaf(wl[64+16*c+12], v3.x, a3);
                a3 = fmaf(wl[64+16*c+13], v3.y, a3);
                a3 = fmaf(wl[64+16*c+14], v3.z, a3);
                a3 = fmaf(wl[64+16*c+15], v3.w, a3);
            }
            float la = lk((a0 + a1) + (a2 + a3));  // first leaky -> x(t+1) and ys[t]
            xbuf[row][lane] = la;
            __syncthreads();   // C: x(t+1) published
            // fused epilogue: second leaky + Linear(H->F) + sigmoid; overlaps
            // the gate waves' next x-dot phase
            float po = 0.f;
#pragma unroll
            for (int c = 0; c < 8; ++c) {
                const float4 v = xr4[half * 8 + c];
                po = fmaf(wo[4*c+0], lk(v.x), po);
                po = fmaf(wo[4*c+1], lk(v.y), po);
                po = fmaf(wo[4*c+2], lk(v.z), po);
                po = fmaf(wo[4*c+3], lk(v.w), po);
            }
            po += __shfl_xor(po, 32);
            float y = sigm(po + bo);
            if (half == 0) orow[t * NF + f] = y;
        }
    }
}

extern "C" void kernel_launch(void* const* d_in, const int* in_sizes, int n_in,
                              void* d_out, int out_size, void* d_ws, size_t ws_size,
                              hipStream_t stream) {
    const float* noise = (const float*)d_in[0];
    const float* Wihf  = (const float*)d_in[1];
    const float* Whhf  = (const float*)d_in[2];
    const float* bihf  = (const float*)d_in[3];
    const float* bhhf  = (const float*)d_in[4];
    const float* Wihb  = (const float*)d_in[5];
    const float* Whhb  = (const float*)d_in[6];
    const float* bihb  = (const float*)d_in[7];
    const float* bhhb  = (const float*)d_in[8];
    const float* Wlat  = (const float*)d_in[9];
    const float* blat  = (const float*)d_in[10];
    const float* Wout  = (const float*)d_in[11];
    const float* bout  = (const float*)d_in[12];

    grugan_kernel<<<dim3(NB / 2), dim3(512), 0, stream>>>(
        noise, Wihf, Whhf, bihf, bhhf, Wihb, Whhb, bihb, bhhb,
        Wlat, blat, Wout, bout, (float*)d_out);
}

// Round 3
// 3299.204 us; speedup vs baseline: 1.6235x; 1.0362x over previous
//
#include <hip/hip_runtime.h>

// GRU-GAN generator, MI355X. Round 3.
// B=512 rows, H=64, S=2048 steps, F=32 outputs.
// 256 blocks x 1024 threads (16 waves, 4/SIMD -> hard 128-VGPR cap); block = 2 rows.
//   waves 0-11: (dir, gate, out-block) gate dots, k-split across lane halves:
//               lane owns output j and k-half kh=lane>>5 -> only 64 weight
//               floats/lane (R2: 128/lane never fit -> 1 GB/launch of reloads).
//   waves 12-15: (row, out-half) latent linear (k-half = one GRU direction)
//               + fused out-projection (4-lane k-split) + sigmoid + store.
// Partial dots combined with __shfl_xor(.,32) (and .,16 for out-proj).
// Barriers: 3/step, matched counts on every wave-uniform divergent path.
// State reads from LDS are wave-uniform/2-way-broadcast addresses (conflict-free).

#define NB 512
#define NH 64
#define NS 2048
#define NF 32

__device__ __forceinline__ float lk(float v) { return fmaxf(v, 0.01f * v); }

__device__ __forceinline__ float sigm(float v) {
    float e = __expf(-v);
    return __builtin_amdgcn_rcpf(1.f + e);
}

__device__ __forceinline__ float tanh_fast(float v) {
    // tanh(v) = 1 - 2/(exp(2v)+1); overflow -> inf -> rcp -> 0 -> 1 (correct limit)
    float e = __expf(v + v);
    return 1.f - 2.f * __builtin_amdgcn_rcpf(e + 1.f);
}

__global__ __launch_bounds__(1024)
void grugan_kernel(const float* __restrict__ noise,
                   const float* __restrict__ Wihf, const float* __restrict__ Whhf,
                   const float* __restrict__ bihf, const float* __restrict__ bhhf,
                   const float* __restrict__ Wihb, const float* __restrict__ Whhb,
                   const float* __restrict__ bihb, const float* __restrict__ bhhb,
                   const float* __restrict__ Wlat, const float* __restrict__ blat,
                   const float* __restrict__ Wout, const float* __restrict__ bout,
                   float* __restrict__ out)
{
    __shared__ float xbuf[2][NH];         // [row][i]  x(t) = lat after ONE leaky
    __shared__ float hbuf[2][2][NH];      // [dir][row][i] h(t)
    __shared__ float rzbuf[2][2][2][NH];  // [dir][gate r=0/z=1][row][j]

    const int tid  = threadIdx.x;
    const int wave = tid >> 6;
    const int lane = tid & 63;
    const int row0 = blockIdx.x * 2;

    // init: x0 = 0, h_fwd = h_bwd = noise
    if (wave == 0) {
        xbuf[0][lane] = 0.f;
        xbuf[1][lane] = 0.f;
    } else if (wave <= 4) {
        int d = (wave - 1) >> 1, r = (wave - 1) & 1;
        hbuf[d][r][lane] = noise[(row0 + r) * NH + lane];
    }
    __syncthreads();

    if (wave < 12) {
        // ---------------- gate waves ----------------
        const int dir = wave / 6;          // 0 fwd, 1 bwd
        const int r6  = wave % 6;
        const int g   = r6 >> 1;           // 0=r 1=z 2=n
        const int ob  = r6 & 1;            // output block (32 outputs each)
        const int jj  = ob * 32 + (lane & 31);  // output index within H
        const int j   = g * 64 + jj;            // row of W_ih / W_hh
        const int kh  = lane >> 5;              // k-half this lane covers
        const int kbase = kh * 32;

        const float* Wih = dir ? Wihb : Wihf;
        const float* Whh = dir ? Whhb : Whhf;

        float wih[32], whh[32];
        {
            const float4* wi4 = (const float4*)(Wih + j * 64 + kbase);
            const float4* wh4 = (const float4*)(Whh + j * 64 + kbase);
#pragma unroll
            for (int c = 0; c < 8; ++c) {
                float4 a = wi4[c];
                wih[4*c+0] = a.x; wih[4*c+1] = a.y; wih[4*c+2] = a.z; wih[4*c+3] = a.w;
                float4 b = wh4[c];
                whh[4*c+0] = b.x; whh[4*c+1] = b.y; whh[4*c+2] = b.z; whh[4*c+3] = b.w;
            }
        }
        const float bi = (dir ? bihb : bihf)[j];
        const float bh = (dir ? bhhb : bhhf)[j];

        float hp0 = 0.f, hp1 = 0.f;   // n-waves keep hidden state in registers
        if (g == 2) {
            hp0 = noise[(row0 + 0) * NH + jj];
            hp1 = noise[(row0 + 1) * NH + jj];
        }

        const float4* x0p = (const float4*)(xbuf[0] + kbase);
        const float4* x1p = (const float4*)(xbuf[1] + kbase);
        const float4* h0p = (const float4*)(hbuf[dir][0] + kbase);
        const float4* h1p = (const float4*)(hbuf[dir][1] + kbase);

        // prologue: h-dot partials for t=0 from initial h (= noise)
        float ah0 = 0.f, ah1 = 0.f;
#pragma unroll
        for (int c = 0; c < 8; ++c) {
            const float4 ha = h0p[c];
            const float4 hc = h1p[c];
            ah0 = fmaf(whh[4*c+0], ha.x, ah0);
            ah0 = fmaf(whh[4*c+1], ha.y, ah0);
            ah0 = fmaf(whh[4*c+2], ha.z, ah0);
            ah0 = fmaf(whh[4*c+3], ha.w, ah0);
            ah1 = fmaf(whh[4*c+0], hc.x, ah1);
            ah1 = fmaf(whh[4*c+1], hc.y, ah1);
            ah1 = fmaf(whh[4*c+2], hc.z, ah1);
            ah1 = fmaf(whh[4*c+3], hc.w, ah1);
        }

        for (int t = 0; t < NS; ++t) {
            // x(t) ready (barrier C of prev step / init). x-dot partials:
            float ai0 = 0.f, ai1 = 0.f;
#pragma unroll
            for (int c = 0; c < 8; ++c) {
                const float4 xa = x0p[c];
                const float4 xb = x1p[c];
                ai0 = fmaf(wih[4*c+0], xa.x, ai0);
                ai0 = fmaf(wih[4*c+1], xa.y, ai0);
                ai0 = fmaf(wih[4*c+2], xa.z, ai0);
                ai0 = fmaf(wih[4*c+3], xa.w, ai0);
                ai1 = fmaf(wih[4*c+0], xb.x, ai1);
                ai1 = fmaf(wih[4*c+1], xb.y, ai1);
                ai1 = fmaf(wih[4*c+2], xb.z, ai1);
                ai1 = fmaf(wih[4*c+3], xb.w, ai1);
            }
            if (g < 2) {
                float s0 = ai0 + ah0;
                float s1 = ai1 + ah1;
                s0 += __shfl_xor(s0, 32);
                s1 += __shfl_xor(s1, 32);
                float v0 = sigm(s0 + bi + bh);
                float v1 = sigm(s1 + bi + bh);
                if (kh == 0) {
                    rzbuf[dir][g][0][jj] = v0;
                    rzbuf[dir][g][1][jj] = v1;
                }
            }
            __syncthreads();   // A: r,z visible
            if (g == 2) {
                float aif0 = ai0 + __shfl_xor(ai0, 32);
                float aif1 = ai1 + __shfl_xor(ai1, 32);
                float ahf0 = ah0 + __shfl_xor(ah0, 32);
                float ahf1 = ah1 + __shfl_xor(ah1, 32);
                float r0 = rzbuf[dir][0][0][jj], r1 = rzbuf[dir][0][1][jj];
                float z0 = rzbuf[dir][1][0][jj], z1 = rzbuf[dir][1][1][jj];
                float n0 = tanh_fast(aif0 + bi + r0 * (ahf0 + bh));
                float n1 = tanh_fast(aif1 + bi + r1 * (ahf1 + bh));
                hp0 = n0 + z0 * (hp0 - n0);   // (1-z)*n + z*h
                hp1 = n1 + z1 * (hp1 - n1);
                if (kh == 0) hbuf[dir][0][jj] = hp0;
                else         hbuf[dir][1][jj] = hp1;
            }
            __syncthreads();   // B: h(t+1) visible
            // h-dot partials for t+1 — overlaps latent wave computing x(t+1)
            ah0 = 0.f; ah1 = 0.f;
#pragma unroll
            for (int c = 0; c < 8; ++c) {
                const float4 ha = h0p[c];
                const float4 hc = h1p[c];
                ah0 = fmaf(whh[4*c+0], ha.x, ah0);
                ah0 = fmaf(whh[4*c+1], ha.y, ah0);
                ah0 = fmaf(whh[4*c+2], ha.z, ah0);
                ah0 = fmaf(whh[4*c+3], ha.w, ah0);
                ah1 = fmaf(whh[4*c+0], hc.x, ah1);
                ah1 = fmaf(whh[4*c+1], hc.y, ah1);
                ah1 = fmaf(whh[4*c+2], hc.z, ah1);
                ah1 = fmaf(whh[4*c+3], hc.w, ah1);
            }
            __syncthreads();   // C: x(t+1) visible
        }
    } else {
        // ------------- latent/output waves: (row, out-half) -------------
        const int lw  = wave - 12;
        const int row = lw >> 1;
        const int oh  = lw & 1;
        const int o   = oh * 32 + (lane & 31);  // latent output index
        const int kh  = lane >> 5;              // k-half == GRU direction

        float wl[64];
        {
            const float4* wl4 = (const float4*)(Wlat + o * 128 + kh * 64);
#pragma unroll
            for (int c = 0; c < 16; ++c) {
                float4 a = wl4[c];
                wl[4*c+0] = a.x; wl[4*c+1] = a.y; wl[4*c+2] = a.z; wl[4*c+3] = a.w;
            }
        }
        const float bl = blat[o];

        const int f = oh * 16 + (lane & 15);    // out-proj feature
        const int q = lane >> 4;                // k-quarter (16 each)
        float wo[16];
        {
            const float4* wo4 = (const float4*)(Wout + f * 64 + q * 16);
#pragma unroll
            for (int c = 0; c < 4; ++c) {
                float4 a = wo4[c];
                wo[4*c+0] = a.x; wo[4*c+1] = a.y; wo[4*c+2] = a.z; wo[4*c+3] = a.w;
            }
        }
        const float bo = bout[f];
        float* orow = out + (size_t)(row0 + row) * NS * NF;

        const float4* hx4 = (const float4*)(hbuf[kh][row]);      // lane's dir
        const float4* xr4 = (const float4*)(xbuf[row] + q * 16);

        for (int t = 0; t < NS; ++t) {
            __syncthreads();   // A
            __syncthreads();   // B: h(t+1) ready
            float a0 = 0.f, a1 = 0.f;
#pragma unroll
            for (int c = 0; c < 8; ++c) {
                const float4 v0 = hx4[2*c+0];
                const float4 v1 = hx4[2*c+1];
                a0 = fmaf(wl[8*c+0], v0.x, a0);
                a0 = fmaf(wl[8*c+1], v0.y, a0);
                a0 = fmaf(wl[8*c+2], v0.z, a0);
                a0 = fmaf(wl[8*c+3], v0.w, a0);
                a1 = fmaf(wl[8*c+4], v1.x, a1);
                a1 = fmaf(wl[8*c+5], v1.y, a1);
                a1 = fmaf(wl[8*c+6], v1.z, a1);
                a1 = fmaf(wl[8*c+7], v1.w, a1);
            }
            float s = a0 + a1;
            s += __shfl_xor(s, 32);
            float la = lk(s + bl);   // first leaky -> x(t+1) and ys[t]
            if (kh == 0) xbuf[row][o] = la;
            __syncthreads();   // C: x(t+1) published
            // fused epilogue: second leaky + Linear(H->F) + sigmoid;
            // overlaps gate waves' next x-dot phase
            float po = 0.f;
#pragma unroll
            for (int c = 0; c < 4; ++c) {
                const float4 v = xr4[c];
                po = fmaf(wo[4*c+0], lk(v.x), po);
                po = fmaf(wo[4*c+1], lk(v.y), po);
                po = fmaf(wo[4*c+2], lk(v.z), po);
                po = fmaf(wo[4*c+3], lk(v.w), po);
            }
            po += __shfl_xor(po, 16);
            po += __shfl_xor(po, 32);
            float y = sigm(po + bo);
            if (q == 0) orow[t * NF + f] = y;
        }
    }
}

extern "C" void kernel_launch(void* const* d_in, const int* in_sizes, int n_in,
                              void* d_out, int out_size, void* d_ws, size_t ws_size,
                              hipStream_t stream) {
    const float* noise = (const float*)d_in[0];
    const float* Wihf  = (const float*)d_in[1];
    const float* Whhf  = (const float*)d_in[2];
    const float* bihf  = (const float*)d_in[3];
    const float* bhhf  = (const float*)d_in[4];
    const float* Wihb  = (const float*)d_in[5];
    const float* Whhb  = (const float*)d_in[6];
    const float* bihb  = (const float*)d_in[7];
    const float* bhhb  = (const float*)d_in[8];
    const float* Wlat  = (const float*)d_in[9];
    const float* blat  = (const float*)d_in[10];
    const float* Wout  = (const float*)d_in[11];
    const float* bout  = (const float*)d_in[12];

    grugan_kernel<<<dim3(NB / 2), dim3(1024), 0, stream>>>(
        noise, Wihf, Whhf, bihf, bhhf, Wihb, Whhb, bihb, bhhb,
        Wlat, blat, Wout, bout, (float*)d_out);
}

// Round 4
// 2066.898 us; speedup vs baseline: 2.5914x; 1.5962x over previous
//
#include <hip/hip_runtime.h>

// GRU-GAN generator, MI355X. Round 4 — MFMA restructure.
// B=512, H=64, S=2048, F=32.
// 32 blocks x 512 threads; block = 16 batch rows (one M=16 MFMA tile).
// 8 waves: each owns (dir = w>>2, colblock cb = w&3) and computes r,z,n gates
// for its 16 hidden cols via v_mfma_f32_16x16x32_bf16 (weights live in 12
// B-fragments = 48 VGPR/lane — small named vectors the RA keeps resident,
// unlike R1-R3's float[64] arrays which it sank into the loop: FETCH ~1GB).
// h is kept fp32 in registers (C-layout, 4 rows/lane); states cross steps
// through LDS as bf16 in A-operand row-major layout (stride 72 shorts=144B,
// <=2-way bank aliasing = free).
// Step pipeline (2 barriers):
//   gates window: [store y(t-2)] -> gi,gh MFMAs -> gates -> h(t+1) -> LDS
//   barrier1
//   latent window: waves0-3 latent K=128 MFMA -> x(t+1)=lk(lat) -> Xs, X2s=lk(x)
//                  waves4-5 out-proj of step t-1 from X2s ping-pong (overlap)
//   barrier2
// Hs and X2s are ping-pong buffered by t parity (no intra-window races).

#define NBATCH 512
#define NH 64
#define NS 2048
#define NF 32
#define MROW 16
#define LDH 72   // padded LDS row stride (shorts): 144 B, breaks pow2 banks

typedef short s16x8 __attribute__((ext_vector_type(8)));
typedef float f32x4 __attribute__((ext_vector_type(4)));

#define MFMA(a, b, c) __builtin_amdgcn_mfma_f32_16x16x32_bf16((a), (b), (c), 0, 0, 0)

__device__ __forceinline__ short f2bf(float f) {
    unsigned u = __float_as_uint(f);
    unsigned r = (u + 0x7FFFu + ((u >> 16) & 1u)) >> 16;  // RNE
    return (short)r;
}

__device__ __forceinline__ float lk(float v) { return fmaxf(v, 0.01f * v); }

__device__ __forceinline__ float sigm(float v) {
    float e = __expf(-v);
    return __builtin_amdgcn_rcpf(1.f + e);
}

__device__ __forceinline__ float tanh_fast(float v) {
    // tanh(v) = 1 - 2/(exp(2v)+1); overflow -> inf -> rcp -> 0 -> 1 (correct limit)
    float e = __expf(v + v);
    return 1.f - 2.f * __builtin_amdgcn_rcpf(e + 1.f);
}

// B-fragment for 16x16x32 bf16 MFMA: lane holds B[k = quad*8+j][n = lane&15],
// i.e. 8 consecutive k's of W^T column (j0+n)  ==  8 consecutive elements of
// row (j0+n) of row-major W. Loaded from global fp32, converted to bf16 once.
__device__ __forceinline__ s16x8 bfragW(const float* __restrict__ W, int ldk,
                                        int row, int kf, int quad) {
    const float* p = W + (size_t)row * ldk + kf * 32 + quad * 8;
    s16x8 r;
#pragma unroll
    for (int i = 0; i < 8; ++i) r[i] = f2bf(p[i]);
    return r;
}

__global__ __launch_bounds__(512)
void grugan_kernel(const float* __restrict__ noise,
                   const float* __restrict__ Wihf, const float* __restrict__ Whhf,
                   const float* __restrict__ bihf, const float* __restrict__ bhhf,
                   const float* __restrict__ Wihb, const float* __restrict__ Whhb,
                   const float* __restrict__ bihb, const float* __restrict__ bhhb,
                   const float* __restrict__ Wlat, const float* __restrict__ blat,
                   const float* __restrict__ Wout, const float* __restrict__ bout,
                   float* __restrict__ out)
{
    __shared__ __align__(16) short Xs[MROW][LDH];          // x(t), bf16, 1 leaky
    __shared__ __align__(16) short X2s[2][MROW][LDH];      // lk(x(t)), ping-pong
    __shared__ __align__(16) short Hs[2][2][MROW][LDH];    // [t&1][dir][m][k]

    const int tid  = threadIdx.x;
    const int wave = tid >> 6;
    const int lane = tid & 63;
    const int n    = lane & 15;   // tile col (N dim) / A row (M dim)
    const int quad = lane >> 4;
    const int row0 = blockIdx.x * MROW;

    // ---- gate role: all 8 waves ----
    const int dir = wave >> 2;      // 0 fwd, 1 bwd
    const int cb  = wave & 3;       // 16-col block of hidden state
    const int jc  = cb * 16 + n;    // owned hidden col
    const float* Wih = dir ? Wihb : Wihf;
    const float* Whh = dir ? Whhb : Whhf;
    const float* bih = dir ? bihb : bihf;
    const float* bhh = dir ? bhhb : bhhf;

    // 12 weight fragments (48 VGPR) — whole gate weight set for this wave
    s16x8 wir0 = bfragW(Wih, NH,   0 + jc, 0, quad);
    s16x8 wir1 = bfragW(Wih, NH,   0 + jc, 1, quad);
    s16x8 wiz0 = bfragW(Wih, NH,  64 + jc, 0, quad);
    s16x8 wiz1 = bfragW(Wih, NH,  64 + jc, 1, quad);
    s16x8 win0 = bfragW(Wih, NH, 128 + jc, 0, quad);
    s16x8 win1 = bfragW(Wih, NH, 128 + jc, 1, quad);
    s16x8 whr0 = bfragW(Whh, NH,   0 + jc, 0, quad);
    s16x8 whr1 = bfragW(Whh, NH,   0 + jc, 1, quad);
    s16x8 whz0 = bfragW(Whh, NH,  64 + jc, 0, quad);
    s16x8 whz1 = bfragW(Whh, NH,  64 + jc, 1, quad);
    s16x8 whn0 = bfragW(Whh, NH, 128 + jc, 0, quad);
    s16x8 whn1 = bfragW(Whh, NH, 128 + jc, 1, quad);
    const float brz_r = bih[jc]       + bhh[jc];
    const float brz_z = bih[64 + jc]  + bhh[64 + jc];
    const float bin   = bih[128 + jc];
    const float bhn   = bhh[128 + jc];

    // ---- latent role (waves 0-3); safe-indexed loads for all waves ----
    const int n0 = (wave & 3) * 16;
    s16x8 wl0 = bfragW(Wlat, 2 * NH, n0 + n, 0, quad);
    s16x8 wl1 = bfragW(Wlat, 2 * NH, n0 + n, 1, quad);
    s16x8 wl2 = bfragW(Wlat, 2 * NH, n0 + n, 2, quad);
    s16x8 wl3 = bfragW(Wlat, 2 * NH, n0 + n, 3, quad);
    const float bl = blat[n0 + n];

    // ---- out-proj role (waves 4,5); safe-indexed loads for all waves ----
    const int f0 = (wave & 1) * 16;
    s16x8 wo0 = bfragW(Wout, NH, f0 + n, 0, quad);
    s16x8 wo1 = bfragW(Wout, NH, f0 + n, 1, quad);
    const float bo = bout[f0 + n];

    // ---- state init: x0 = 0; h = noise (fp32 in regs, bf16 copy in Hs[0]) ----
    for (int idx = tid; idx < MROW * LDH; idx += 512) (&Xs[0][0])[idx] = 0;
    float hreg[4];
#pragma unroll
    for (int i = 0; i < 4; ++i) {
        hreg[i] = noise[(size_t)(row0 + quad * 4 + i) * NH + jc];
        Hs[0][dir][quad * 4 + i][jc] = f2bf(hreg[i]);
    }
    __syncthreads();

    f32x4 yv = {0.f, 0.f, 0.f, 0.f};   // pending out values (waves 4,5)

    for (int t = 0; t < NS; ++t) {
        const int hb = t & 1;
        // ---------------- gates window ----------------
        // store y for step t-2 (computed in latent window t-1); the store's
        // vmcnt drain lands at barrier1, absorbed by ~300cy of gate work
        if (t >= 2 && (wave == 4 || wave == 5)) {
            const size_t tb = (size_t)(t - 2) * NF + f0 + n;
#pragma unroll
            for (int i = 0; i < 4; ++i)
                out[(size_t)(row0 + quad * 4 + i) * (NS * NF) + tb] = yv[i];
        }
        // A-frags: rows m = lane&15
        s16x8 xa0 = *(const s16x8*)&Xs[n][quad * 8];
        s16x8 xa1 = *(const s16x8*)&Xs[n][32 + quad * 8];
        s16x8 ha0 = *(const s16x8*)&Hs[hb][dir][n][quad * 8];
        s16x8 ha1 = *(const s16x8*)&Hs[hb][dir][n][32 + quad * 8];
        f32x4 gr = {0.f, 0.f, 0.f, 0.f}, gz = gr, gn = gr;
        f32x4 hr = gr, hz = gr, hn = gr;
        gr = MFMA(xa0, wir0, gr); gr = MFMA(xa1, wir1, gr);
        gz = MFMA(xa0, wiz0, gz); gz = MFMA(xa1, wiz1, gz);
        gn = MFMA(xa0, win0, gn); gn = MFMA(xa1, win1, gn);
        hr = MFMA(ha0, whr0, hr); hr = MFMA(ha1, whr1, hr);
        hz = MFMA(ha0, whz0, hz); hz = MFMA(ha1, whz1, hz);
        hn = MFMA(ha0, whn0, hn); hn = MFMA(ha1, whn1, hn);
        // gates + h update; C layout: row = quad*4+i, col = jc
#pragma unroll
        for (int i = 0; i < 4; ++i) {
            float r  = sigm(gr[i] + hr[i] + brz_r);
            float z  = sigm(gz[i] + hz[i] + brz_z);
            float nn = tanh_fast(gn[i] + bin + r * (hn[i] + bhn));
            float hv = nn + z * (hreg[i] - nn);   // (1-z)n + z h
            hreg[i] = hv;
            Hs[hb ^ 1][dir][quad * 4 + i][jc] = f2bf(hv);
        }
        __syncthreads();   // barrier1: H(t+1) visible
        // ---------------- latent window ----------------
        if (wave < 4) {
            s16x8 fa0 = *(const s16x8*)&Hs[hb ^ 1][0][n][quad * 8];
            s16x8 fa1 = *(const s16x8*)&Hs[hb ^ 1][0][n][32 + quad * 8];
            s16x8 ba0 = *(const s16x8*)&Hs[hb ^ 1][1][n][quad * 8];
            s16x8 ba1 = *(const s16x8*)&Hs[hb ^ 1][1][n][32 + quad * 8];
            f32x4 ac0 = {0.f, 0.f, 0.f, 0.f}, ac1 = ac0;
            ac0 = MFMA(fa0, wl0, ac0); ac0 = MFMA(fa1, wl1, ac0);
            ac1 = MFMA(ba0, wl2, ac1); ac1 = MFMA(ba1, wl3, ac1);
#pragma unroll
            for (int i = 0; i < 4; ++i) {
                float la = lk(ac0[i] + ac1[i] + bl);   // ys[t] = x(t+1)
                Xs[quad * 4 + i][n0 + n]          = f2bf(la);
                X2s[hb ^ 1][quad * 4 + i][n0 + n] = f2bf(lk(la));
            }
        } else if (wave < 6 && t >= 1) {
            // out-proj for step t-1: input lk(x(t)) = X2s[t&1]
            s16x8 p0 = *(const s16x8*)&X2s[hb][n][quad * 8];
            s16x8 p1 = *(const s16x8*)&X2s[hb][n][32 + quad * 8];
            f32x4 po = {0.f, 0.f, 0.f, 0.f};
            po = MFMA(p0, wo0, po); po = MFMA(p1, wo1, po);
#pragma unroll
            for (int i = 0; i < 4; ++i) yv[i] = sigm(po[i] + bo);
        }
        __syncthreads();   // barrier2: x(t+1) visible
    }

    // ---------------- epilogue (waves 4,5) ----------------
    if (wave == 4 || wave == 5) {
        // store out-row NS-2 (computed in latent window NS-1)
        {
            const size_t tb = (size_t)(NS - 2) * NF + f0 + n;
#pragma unroll
            for (int i = 0; i < 4; ++i)
                out[(size_t)(row0 + quad * 4 + i) * (NS * NF) + tb] = yv[i];
        }
        // compute + store out-row NS-1 from X2s[NS&1] = X2s[0]
        s16x8 p0 = *(const s16x8*)&X2s[0][n][quad * 8];
        s16x8 p1 = *(const s16x8*)&X2s[0][n][32 + quad * 8];
        f32x4 po = {0.f, 0.f, 0.f, 0.f};
        po = MFMA(p0, wo0, po); po = MFMA(p1, wo1, po);
        const size_t tb = (size_t)(NS - 1) * NF + f0 + n;
#pragma unroll
        for (int i = 0; i < 4; ++i)
            out[(size_t)(row0 + quad * 4 + i) * (NS * NF) + tb] = sigm(po[i] + bo);
    }
}

extern "C" void kernel_launch(void* const* d_in, const int* in_sizes, int n_in,
                              void* d_out, int out_size, void* d_ws, size_t ws_size,
                              hipStream_t stream) {
    const float* noise = (const float*)d_in[0];
    const float* Wihf  = (const float*)d_in[1];
    const float* Whhf  = (const float*)d_in[2];
    const float* bihf  = (const float*)d_in[3];
    const float* bhhf  = (const float*)d_in[4];
    const float* Wihb  = (const float*)d_in[5];
    const float* Whhb  = (const float*)d_in[6];
    const float* bihb  = (const float*)d_in[7];
    const float* bhhb  = (const float*)d_in[8];
    const float* Wlat  = (const float*)d_in[9];
    const float* blat  = (const float*)d_in[10];
    const float* Wout  = (const float*)d_in[11];
    const float* bout  = (const float*)d_in[12];

    grugan_kernel<<<dim3(NBATCH / MROW), dim3(512), 0, stream>>>(
        noise, Wihf, Whhf, bihf, bhhf, Wihb, Whhb, bihb, bhhb,
        Wlat, blat, Wout, bout, (float*)d_out);
}